// Round 1
// baseline (643.323 us; speedup 1.0000x reference)
//
#include <hip/hip_runtime.h>
#include <hip/hip_bf16.h>

// y[m][o] = sum_i x[m][i] * (w[o][i] * sinv[o/128][i/128])
// M=32, K=7168, O(N)=16384. Memory-bound on streaming W (470 MB f32).

typedef short short8 __attribute__((ext_vector_type(8)));   // 8 bf16 in 4 VGPRs
typedef float f32x4 __attribute__((ext_vector_type(4)));

constexpr int M = 32;
constexpr int K = 7168;
constexpr int N = 16384;
constexpr int SPLIT = 4;                 // K split into 4 chunks of 1792
constexpr int KCHUNK = K / SPLIT;        // 1792 = 14 scale-blocks of 128
constexpr int SCOLS = K / 128;           // 56

__device__ __forceinline__ short bf16_of(float f) {
    __hip_bfloat16 h = __float2bfloat16(f);   // RNE; compiler packs to v_cvt_pk_bf16_f32
    return *reinterpret_cast<short*>(&h);
}

__global__ __launch_bounds__(256) void gemm_dq(const float* __restrict__ x,
                                               const float* __restrict__ w,
                                               const float* __restrict__ sinv,
                                               float* __restrict__ out)
{
    const int wid  = threadIdx.x >> 6;       // wave 0..3
    const int lane = threadIdx.x & 63;
    const int r    = lane & 15;              // A-row / B-col within fragment
    const int h    = lane >> 4;              // k-subgroup 0..3 (8 contiguous k each)
    const int otile = blockIdx.x * 64 + wid * 16;
    const int srow  = otile >> 7;            // scale row (o / 128), wave-uniform
    const int k0    = blockIdx.y * KCHUNK;

    const float* xp0 = x + (size_t)r * K;          // x rows 0..15
    const float* xp1 = x + (size_t)(16 + r) * K;   // x rows 16..31
    const float* wp  = w + (size_t)(otile + r) * K;

    f32x4 acc0 = {0.f, 0.f, 0.f, 0.f};
    f32x4 acc1 = {0.f, 0.f, 0.f, 0.f};

    for (int sb = 0; sb < KCHUNK / 128; ++sb) {
        const float s = sinv[srow * SCOLS + (k0 >> 7) + sb];   // wave-uniform scalar
        const int kb = k0 + sb * 128;
        #pragma unroll
        for (int st = 0; st < 4; ++st) {
            const int k = kb + st * 32 + h * 8;    // this lane's 8 contiguous k
            // B: 8 contiguous f32 from this output row of W (HBM stream)
            f32x4 b0 = *(const f32x4*)(wp + k);
            f32x4 b1 = *(const f32x4*)(wp + k + 4);
            // A: 8 contiguous f32 from x rows r and r+16 (L1/L2-resident)
            f32x4 a0 = *(const f32x4*)(xp0 + k);
            f32x4 a1 = *(const f32x4*)(xp0 + k + 4);
            f32x4 c0 = *(const f32x4*)(xp1 + k);
            f32x4 c1 = *(const f32x4*)(xp1 + k + 4);

            short8 bf, af, cf;
            #pragma unroll
            for (int j = 0; j < 4; ++j) {
                bf[j]     = bf16_of(b0[j] * s);
                bf[j + 4] = bf16_of(b1[j] * s);
                af[j]     = bf16_of(a0[j]);
                af[j + 4] = bf16_of(a1[j]);
                cf[j]     = bf16_of(c0[j]);
                cf[j + 4] = bf16_of(c1[j]);
            }
            acc0 = __builtin_amdgcn_mfma_f32_16x16x32_bf16(af, bf, acc0, 0, 0, 0);
            acc1 = __builtin_amdgcn_mfma_f32_16x16x32_bf16(cf, bf, acc1, 0, 0, 0);
        }
    }

    // C/D layout (verified m89/m91): col = lane&15, row = (lane>>4)*4 + reg
    const int o = otile + r;
    #pragma unroll
    for (int j = 0; j < 4; ++j) {
        const int m0 = h * 4 + j;
        atomicAdd(&out[(size_t)m0 * N + o],        acc0[j]);
        atomicAdd(&out[(size_t)(16 + m0) * N + o], acc1[j]);
    }
}

extern "C" void kernel_launch(void* const* d_in, const int* in_sizes, int n_in,
                              void* d_out, int out_size, void* d_ws, size_t ws_size,
                              hipStream_t stream) {
    const float* x    = (const float*)d_in[0];
    const float* w    = (const float*)d_in[1];
    const float* sinv = (const float*)d_in[2];
    float* out = (float*)d_out;

    hipMemsetAsync(out, 0, (size_t)M * N * sizeof(float), stream);

    dim3 grid(N / 64, SPLIT);
    gemm_dq<<<grid, 256, 0, stream>>>(x, w, sinv, out);
}

// Round 2
// 617.930 us; speedup vs baseline: 1.0411x; 1.0411x over previous
//
#include <hip/hip_runtime.h>
#include <hip/hip_bf16.h>

// y[m][o] = sum_i x[m][i] * (w[o][i] * sinv[o/128][i/128])
// M=32, K=7168, N=16384. Memory-bound: stream W (470 MB f32) once.
// x is staged per-block into LDS as bf16 in MFMA A-fragment order.

typedef short short8 __attribute__((ext_vector_type(8)));   // 8 bf16
typedef float f32x4 __attribute__((ext_vector_type(4)));

constexpr int M = 32;
constexpr int K = 7168;
constexpr int N = 16384;
constexpr int SPLIT = 4;                 // K split across blockIdx.y
constexpr int KCHUNK = K / SPLIT;        // 1792 = 14 scale-blocks
constexpr int NSB = KCHUNK / 128;        // 14
constexpr int SCOLS = K / 128;           // 56

__device__ __forceinline__ short bf16_of(float f) {
    __hip_bfloat16 h = __float2bfloat16(f);   // RNE; pairs fuse to v_cvt_pk_bf16_f32
    return *reinterpret_cast<short*>(&h);
}

__global__ __launch_bounds__(256) void gemm_dq(const float* __restrict__ x,
                                               const float* __restrict__ w,
                                               const float* __restrict__ sinv,
                                               float* __restrict__ out)
{
    // bf16 x slab for one 128-k block, double buffered.
    // Granule g = kg*16 + (row ^ kg)  (kg = k-octet 0..15, row = m row 0..15)
    // -> ds_write: 64 lanes hit each bank-quad exactly 8x (balanced, optimal)
    // -> ds_read (A-frag): 64 lanes read 1 KB contiguous (conflict-free)
    __shared__ short8 xl0[2][256];   // m rows 0..15
    __shared__ short8 xl1[2][256];   // m rows 16..31

    const int tid  = threadIdx.x;
    const int wid  = tid >> 6;
    const int lane = tid & 63;
    const int r    = lane & 15;              // A-row / B-row within fragment
    const int h    = lane >> 4;              // k-subgroup 0..3
    const int otile = blockIdx.x * 64 + wid * 16;
    const int k0    = blockIdx.y * KCHUNK;
    const int srow  = (blockIdx.x * 64) >> 7;       // scale row, block-uniform

    // staging role: thread t handles x rows (t>>4) and (t>>4)+16, k-octet t&15
    const int sxrow = tid >> 4;              // 0..15
    const int skg   = tid & 15;              // 0..15
    const int sgran = skg * 16 + (sxrow ^ skg);
    const float* xs0 = x + (size_t)sxrow * K + k0 + skg * 8;
    const float* xs1 = xs0 + (size_t)16 * K;

    const float* wp = w + (size_t)(otile + r) * K + k0;

    f32x4 acc0 = {0.f,0.f,0.f,0.f};
    f32x4 acc1 = {0.f,0.f,0.f,0.f};

    // ---- prologue: stage sb=0 into buffer 0 ----
    {
        f32x4 a0 = *(const f32x4*)(xs0);
        f32x4 a1 = *(const f32x4*)(xs0 + 4);
        f32x4 c0 = *(const f32x4*)(xs1);
        f32x4 c1 = *(const f32x4*)(xs1 + 4);
        short8 p, q;
        #pragma unroll
        for (int j = 0; j < 4; ++j) {
            p[j] = bf16_of(a0[j]); p[j+4] = bf16_of(a1[j]);
            q[j] = bf16_of(c0[j]); q[j+4] = bf16_of(c1[j]);
        }
        xl0[0][sgran] = p;
        xl1[0][sgran] = q;
    }

    for (int sb = 0; sb < NSB; ++sb) {
        __syncthreads();                      // staged[cur] visible to all waves
        const int cur = sb & 1;

        // stage next 128-k slab into the other buffer (hides under compute)
        if (sb + 1 < NSB) {
            const float* p0 = xs0 + (sb + 1) * 128;
            const float* p1 = xs1 + (sb + 1) * 128;
            f32x4 a0 = *(const f32x4*)(p0);
            f32x4 a1 = *(const f32x4*)(p0 + 4);
            f32x4 c0 = *(const f32x4*)(p1);
            f32x4 c1 = *(const f32x4*)(p1 + 4);
            short8 p, q;
            #pragma unroll
            for (int j = 0; j < 4; ++j) {
                p[j] = bf16_of(a0[j]); p[j+4] = bf16_of(a1[j]);
                q[j] = bf16_of(c0[j]); q[j+4] = bf16_of(c1[j]);
            }
            xl0[cur ^ 1][sgran] = p;
            xl1[cur ^ 1][sgran] = q;
        }

        const float s = sinv[srow * SCOLS + (k0 >> 7) + sb];  // block-uniform
        f32x4 t0 = {0.f,0.f,0.f,0.f};
        f32x4 t1 = {0.f,0.f,0.f,0.f};

        #pragma unroll
        for (int st = 0; st < 4; ++st) {
            const float* wk = wp + sb * 128 + st * 32 + h * 8;
            f32x4 b0 = *(const f32x4*)(wk);
            f32x4 b1 = *(const f32x4*)(wk + 4);
            short8 bf;
            #pragma unroll
            for (int j = 0; j < 4; ++j) {
                bf[j]   = bf16_of(b0[j]);
                bf[j+4] = bf16_of(b1[j]);
            }
            const int kgr = st * 4 + h;
            const int g   = kgr * 16 + (r ^ kgr);
            short8 af = xl0[cur][g];
            short8 cf = xl1[cur][g];
            t0 = __builtin_amdgcn_mfma_f32_16x16x32_bf16(af, bf, t0, 0, 0, 0);
            t1 = __builtin_amdgcn_mfma_f32_16x16x32_bf16(cf, bf, t1, 0, 0, 0);
        }

        // apply dequant scale once per 128-k block
        #pragma unroll
        for (int j = 0; j < 4; ++j) {
            acc0[j] += s * t0[j];
            acc1[j] += s * t1[j];
        }
    }

    // C/D layout (m89/m91): col = lane&15, row = (lane>>4)*4 + reg
    const int o = otile + r;
    #pragma unroll
    for (int j = 0; j < 4; ++j) {
        const int m0 = h * 4 + j;
        atomicAdd(&out[(size_t)m0 * N + o],        acc0[j]);
        atomicAdd(&out[(size_t)(16 + m0) * N + o], acc1[j]);
    }
}

extern "C" void kernel_launch(void* const* d_in, const int* in_sizes, int n_in,
                              void* d_out, int out_size, void* d_ws, size_t ws_size,
                              hipStream_t stream) {
    const float* x    = (const float*)d_in[0];
    const float* w    = (const float*)d_in[1];
    const float* sinv = (const float*)d_in[2];
    float* out = (float*)d_out;

    hipMemsetAsync(out, 0, (size_t)M * N * sizeof(float), stream);

    dim3 grid(N / 64, SPLIT);
    gemm_dq<<<grid, 256, 0, stream>>>(x, w, sinv, out);
}